// Round 6
// baseline (2496.837 us; speedup 1.0000x reference)
//
#include <hip/hip_runtime.h>
#include <math.h>

// TfLSTM: x[512,256,128] -> LSTM(100, relu) -> LSTM(128, relu, last) -> Dense(19) -> softmax
// Round 6: MFMA split-bf16 recurrence. Block = 16 batch rows (grid 32), z = h@U
// via mfma_f32_16x16x32_bf16 with U and h each split into bf16 hi+lo
// (3 products, Al*Bl dropped => ~2^-18 rel err). U-frags live in VGPRs across
// all timesteps (waves_per_eu(1,1) = 512-reg budget, the r5-proven knob).
// Per step: MFMA phase (z into C-layout LDS) -> barrier -> gate/c/h update
// -> barrier. Projections unchanged (r5 fp32 tiles, round-7 target).

#define T_SEQ 256
#define BATCH 512
#define IN_DIM 128
#define H1 100
#define H2 128
#define NCLS 19

typedef float f4v __attribute__((ext_vector_type(4)));
typedef short s8v __attribute__((ext_vector_type(8)));

#define ZERO8 ((s8v){0, 0, 0, 0, 0, 0, 0, 0})
#define REP8S(M) M(0) M(1) M(2) M(3) M(4) M(5) M(6) M(7)

__device__ __forceinline__ float sigmoidf_(float x) {
    return 1.0f / (1.0f + __expf(-x));
}
__device__ __forceinline__ f4v sig4_(f4v z) {
    f4v r;
    r.x = sigmoidf_(z.x); r.y = sigmoidf_(z.y);
    r.z = sigmoidf_(z.z); r.w = sigmoidf_(z.w);
    return r;
}
__device__ __forceinline__ f4v relu4_(f4v z) {
    f4v r;
    r.x = fmaxf(z.x, 0.f); r.y = fmaxf(z.y, 0.f);
    r.z = fmaxf(z.z, 0.f); r.w = fmaxf(z.w, 0.f);
    return r;
}

// round-to-nearest-even fp32 -> bf16 (returned as short) + exact hi float
__device__ __forceinline__ short bf_hi_(float x, float& hif) {
    unsigned u = __builtin_bit_cast(unsigned, x);
    unsigned r = (u + 0x7FFFu + ((u >> 16) & 1u)) & 0xFFFF0000u;
    hif = __builtin_bit_cast(float, r);
    return (short)(r >> 16);
}
__device__ __forceinline__ void bsplit_(float x, short& hi, short& lo) {
    float hif;
    hi = bf_hi_(x, hif);
    float rs = x - hif;   // exact (Sterbenz-range subtraction)
    float d;
    lo = bf_hi_(rs, d);
}

// one-time B-fragment load: B[k][n] from U (K = NU rows, NG cols), split hi/lo.
// 16x16x32 B layout: lane holds B[k = (lane>>4)*8 + j][n = lane&15].
template<int NU, int NG>
__device__ __forceinline__ void load_bfrag_(const float* __restrict__ U,
                                            int k0, int n, s8v& hi, s8v& lo) {
    short hh[8], ll[8];
#pragma unroll
    for (int j = 0; j < 8; ++j) {
        float x = (k0 + j < NU) ? U[(size_t)(k0 + j) * NG + n] : 0.0f;
        bsplit_(x, hh[j], ll[j]);
    }
    hi = (s8v){hh[0], hh[1], hh[2], hh[3], hh[4], hh[5], hh[6], hh[7]};
    lo = (s8v){ll[0], ll[1], ll[2], ll[3], ll[4], ll[5], ll[6], ll[7]};
}

// per-step A-fragment: 8 consecutive fp32 h values from LDS, split hi/lo.
__device__ __forceinline__ void load_afrag_(const float* p, s8v& ah, s8v& al) {
    f4v x0 = *(const f4v*)p;
    f4v x1 = *(const f4v*)(p + 4);
    short h0, h1, h2, h3, h4, h5, h6, h7, l0, l1, l2, l3, l4, l5, l6, l7;
    bsplit_(x0.x, h0, l0); bsplit_(x0.y, h1, l1);
    bsplit_(x0.z, h2, l2); bsplit_(x0.w, h3, l3);
    bsplit_(x1.x, h4, l4); bsplit_(x1.y, h5, l5);
    bsplit_(x1.z, h6, l6); bsplit_(x1.w, h7, l7);
    ah = (s8v){h0, h1, h2, h3, h4, h5, h6, h7};
    al = (s8v){l0, l1, l2, l3, l4, l5, l6, l7};
}

// =================== MFMA LSTM recurrence ===================
// NU: units (100 or 128). Block: 16 batch rows, 256 threads (4 waves).
// Tiles (16 cols each) round-robin: slot s of wave w -> tile 4s+w (skip >= NT).
template<int NU, bool SEQOUT, bool INIT, bool WRSTATE, bool WROUT>
__global__ __launch_bounds__(256)
__attribute__((amdgpu_waves_per_eu(1, 1)))
void recm_kernel(const float* __restrict__ zx,   // [tlen][B][NG] (bias included)
                 const float* __restrict__ U,    // [NU][NG]
                 float* __restrict__ outp,       // SEQOUT: [tlen][B][NU]; WROUT: [B][NU]
                 float* __restrict__ cbuf,       // [B][NU] chunk carry
                 float* __restrict__ hbuf,       // [B][NU] chunk carry
                 int tlen)
{
    constexpr int NG = 4 * NU;
    constexpr int NT = NG / 16;
    constexpr int ZLD = 20;    // za row stride (floats): 16B-aligned, conflict-light
    constexpr int ALD = 132;   // hA row stride: breaks 16-way b128 conflicts
    __shared__ float za[NG * ZLD];     // [col][row16] funnel
    __shared__ float hA[16 * ALD];     // [row][k] fp32 hidden state

    const int tid = threadIdx.x;
    const int wv = tid >> 6;
    const int lane = tid & 63;
    const int lm = lane & 15;
    const int lq = lane >> 4;
    const int blk16 = blockIdx.x * 16;

    // ---- one-time B-frag load (register-resident across all steps) ----
#define BDECL(s) \
    const int nt##s = 4 * (s) + wv; const bool v##s = (nt##s) < NT; \
    s8v bh##s##_0 = ZERO8, bh##s##_1 = ZERO8, bh##s##_2 = ZERO8, bh##s##_3 = ZERO8; \
    s8v bl##s##_0 = ZERO8, bl##s##_1 = ZERO8, bl##s##_2 = ZERO8, bl##s##_3 = ZERO8; \
    if (v##s) { \
        int nn = nt##s * 16 + lm; \
        load_bfrag_<NU, NG>(U,  0 + lq * 8, nn, bh##s##_0, bl##s##_0); \
        load_bfrag_<NU, NG>(U, 32 + lq * 8, nn, bh##s##_1, bl##s##_1); \
        load_bfrag_<NU, NG>(U, 64 + lq * 8, nn, bh##s##_2, bl##s##_2); \
        load_bfrag_<NU, NG>(U, 96 + lq * 8, nn, bh##s##_3, bl##s##_3); \
    }
    REP8S(BDECL)
#undef BDECL

    // ---- init hidden state ----
    if (INIT) {
        for (int i = tid; i < 16 * ALD; i += 256) hA[i] = 0.0f;
    } else {
        int row = tid >> 4, k8 = (tid & 15) * 8;  // NU==128 path only
        f4v a = *(const f4v*)&hbuf[(size_t)(blk16 + row) * NU + k8];
        f4v b = *(const f4v*)&hbuf[(size_t)(blk16 + row) * NU + k8 + 4];
        *(f4v*)&hA[row * ALD + k8] = a;
        *(f4v*)&hA[row * ALD + k8 + 4] = b;
    }
    f4v c0_ = {0.f, 0.f, 0.f, 0.f}, c1_ = {0.f, 0.f, 0.f, 0.f};
    if (!INIT) {
        {
            int id = tid;
            if (id < NU * 4) {
                int u = id >> 2, rg = id & 3;
                const float* pc = &cbuf[(size_t)(blk16 + rg * 4) * NU + u];
                c0_ = (f4v){pc[0], pc[NU], pc[2 * NU], pc[3 * NU]};
            }
        }
        {
            int id = tid + 256;
            if (id < NU * 4) {
                int u = id >> 2, rg = id & 3;
                const float* pc = &cbuf[(size_t)(blk16 + rg * 4) * NU + u];
                c1_ = (f4v){pc[0], pc[NU], pc[2 * NU], pc[3 * NU]};
            }
        }
    }
    __syncthreads();

#define TRIP(s, kt) \
    acc = __builtin_amdgcn_mfma_f32_16x16x32_bf16(ah##kt, bh##s##_##kt, acc, 0, 0, 0); \
    acc = __builtin_amdgcn_mfma_f32_16x16x32_bf16(al##kt, bh##s##_##kt, acc, 0, 0, 0); \
    acc = __builtin_amdgcn_mfma_f32_16x16x32_bf16(ah##kt, bl##s##_##kt, acc, 0, 0, 0);

#define TILEC(s) \
    if (v##s) { \
        const float* pz = zx + zbase + nt##s * 16; \
        f4v acc = (f4v){pz[0], pz[NG], pz[2 * NG], pz[3 * NG]}; \
        TRIP(s, 0) TRIP(s, 1) TRIP(s, 2) TRIP(s, 3) \
        *(f4v*)&za[(nt##s * 16 + lm) * ZLD + lq * 4] = acc; \
    }

#define UPDATE(a, cr) { \
        int id = tid + 256 * (a); \
        if (id < NU * 4) { \
            int u = id >> 2, rg = id & 3; \
            f4v iv = *(const f4v*)&za[(u         ) * ZLD + rg * 4]; \
            f4v fv = *(const f4v*)&za[(u +     NU) * ZLD + rg * 4]; \
            f4v gv = *(const f4v*)&za[(u + 2 * NU) * ZLD + rg * 4]; \
            f4v ov = *(const f4v*)&za[(u + 3 * NU) * ZLD + rg * 4]; \
            iv = sig4_(iv); fv = sig4_(fv); gv = relu4_(gv); ov = sig4_(ov); \
            cr = fv * cr + iv * gv; \
            f4v hv = ov * relu4_(cr); \
            hA[(rg * 4 + 0) * ALD + u] = hv.x; \
            hA[(rg * 4 + 1) * ALD + u] = hv.y; \
            hA[(rg * 4 + 2) * ALD + u] = hv.z; \
            hA[(rg * 4 + 3) * ALD + u] = hv.w; \
            if (SEQOUT) { \
                float* po = outp + ((size_t)t * BATCH + blk16 + rg * 4) * NU + u; \
                po[0] = hv.x; po[NU] = hv.y; po[2 * NU] = hv.z; po[3 * NU] = hv.w; \
            } \
        } \
    }

#pragma unroll 1
    for (int t = 0; t < tlen; ++t) {
        // A-frags (shared across all this wave's tiles)
        s8v ah0, al0, ah1, al1, ah2, al2, ah3, al3;
        load_afrag_(&hA[lm * ALD +  0 + lq * 8], ah0, al0);
        load_afrag_(&hA[lm * ALD + 32 + lq * 8], ah1, al1);
        load_afrag_(&hA[lm * ALD + 64 + lq * 8], ah2, al2);
        load_afrag_(&hA[lm * ALD + 96 + lq * 8], ah3, al3);

        const size_t zbase = ((size_t)t * BATCH + blk16 + lq * 4) * NG + lm;
        REP8S(TILEC)
        __syncthreads();

        UPDATE(0, c0_)
        UPDATE(1, c1_)
        __syncthreads();
    }
#undef TILEC
#undef TRIP
#undef UPDATE

    if (WRSTATE) {
        {
            int row = tid >> 4, k8 = (tid & 15) * 8;  // NU==128 path
            f4v a = *(const f4v*)&hA[row * ALD + k8];
            f4v b = *(const f4v*)&hA[row * ALD + k8 + 4];
            *(f4v*)&hbuf[(size_t)(blk16 + row) * NU + k8] = a;
            *(f4v*)&hbuf[(size_t)(blk16 + row) * NU + k8 + 4] = b;
        }
        {
            int id = tid;
            if (id < NU * 4) {
                int u = id >> 2, rg = id & 3;
                float* pc = &cbuf[(size_t)(blk16 + rg * 4) * NU + u];
                pc[0] = c0_.x; pc[NU] = c0_.y; pc[2 * NU] = c0_.z; pc[3 * NU] = c0_.w;
            }
        }
        {
            int id = tid + 256;
            if (id < NU * 4) {
                int u = id >> 2, rg = id & 3;
                float* pc = &cbuf[(size_t)(blk16 + rg * 4) * NU + u];
                pc[0] = c1_.x; pc[NU] = c1_.y; pc[2 * NU] = c1_.z; pc[3 * NU] = c1_.w;
            }
        }
    }
    if (WROUT) {
        int row = tid >> 4, k8 = (tid & 15) * 8;  // NU==128 path
        f4v a = *(const f4v*)&hA[row * ALD + k8];
        f4v b = *(const f4v*)&hA[row * ALD + k8 + 4];
        *(f4v*)&outp[(size_t)(blk16 + row) * NU + k8] = a;
        *(f4v*)&outp[(size_t)(blk16 + row) * NU + k8 + 4] = b;
    }
}

// =================== projection GEMM (unchanged, r5) ===================
#define PREP8(M)  M(0) M(1) M(2) M(3) M(4) M(5) M(6) M(7)
template<int K, int N, bool SWAP>
__global__ __launch_bounds__(256, 2)
void proj_kernel(const float* __restrict__ A, const float* __restrict__ W,
                 const float* __restrict__ bias, float* __restrict__ out)
{
    constexpr int LD = 132;
    __shared__ __align__(16) float As[32 * LD];
    __shared__ __align__(16) float Ws[32 * LD];
    const int tid = threadIdx.x;
    const int r0 = blockIdx.x * 128;
    const int c0 = blockIdx.y * 128;
    const int ty = tid >> 4, tx = tid & 15;

#define PACC(i) f4v accL##i = {0.f,0.f,0.f,0.f}; f4v accR##i = {0.f,0.f,0.f,0.f};
    PREP8(PACC)
#undef PACC

    for (int kk = 0; kk < K; kk += 32) {
        __syncthreads();
#pragma unroll
        for (int i = 0; i < 4; ++i) {
            int idx = tid + i * 256;
            int row = idx >> 3, kg = idx & 7;
            int k = kk + kg * 4;
            f4v v = {0.f, 0.f, 0.f, 0.f};
            if (k < K) v = *(const f4v*)&A[(size_t)(r0 + row) * K + k];
            As[(kg * 4 + 0) * LD + row] = v.x;
            As[(kg * 4 + 1) * LD + row] = v.y;
            As[(kg * 4 + 2) * LD + row] = v.z;
            As[(kg * 4 + 3) * LD + row] = v.w;
        }
#pragma unroll
        for (int i = 0; i < 4; ++i) {
            int idx = tid + i * 256;
            int k = idx >> 5, cg = idx & 31;
            int gk = kk + k, gc = c0 + cg * 4;
            f4v v = {0.f, 0.f, 0.f, 0.f};
            if (gk < K && gc < N) v = *(const f4v*)&W[(size_t)gk * N + gc];
            *(f4v*)&Ws[k * LD + cg * 4] = v;
        }
        __syncthreads();
#pragma unroll
        for (int k = 0; k < 32; ++k) {
            f4v av0 = *(const f4v*)&As[k * LD + ty * 8];
            f4v av1 = *(const f4v*)&As[k * LD + ty * 8 + 4];
            f4v b0v = *(const f4v*)&Ws[k * LD + tx * 8];
            f4v b1v = *(const f4v*)&Ws[k * LD + tx * 8 + 4];
#define PFMA(i, s) accL##i += (s) * b0v; accR##i += (s) * b1v;
            PFMA(0, av0.x) PFMA(1, av0.y) PFMA(2, av0.z) PFMA(3, av0.w)
            PFMA(4, av1.x) PFMA(5, av1.y) PFMA(6, av1.z) PFMA(7, av1.w)
#undef PFMA
        }
    }

    const int cb = c0 + tx * 8;
    float b0 = (cb + 0 < N) ? bias[cb + 0] : 0.f;
    float b1 = (cb + 1 < N) ? bias[cb + 1] : 0.f;
    float b2 = (cb + 2 < N) ? bias[cb + 2] : 0.f;
    float b3 = (cb + 3 < N) ? bias[cb + 3] : 0.f;
    float b4 = (cb + 4 < N) ? bias[cb + 4] : 0.f;
    float b5 = (cb + 5 < N) ? bias[cb + 5] : 0.f;
    float b6 = (cb + 6 < N) ? bias[cb + 6] : 0.f;
    float b7 = (cb + 7 < N) ? bias[cb + 7] : 0.f;
    f4v bL = {b0, b1, b2, b3};
    f4v bR = {b4, b5, b6, b7};
#define PST(i) { \
        int r = r0 + ty * 8 + i; \
        size_t orow = SWAP ? ((size_t)(r & 255) * BATCH + (r >> 8)) : (size_t)r; \
        if (cb < N)     { f4v v = accL##i + bL; *(f4v*)&out[orow * N + cb] = v; } \
        if (cb + 4 < N) { f4v v = accR##i + bR; *(f4v*)&out[orow * N + cb + 4] = v; } }
    PREP8(PST)
#undef PST
}

// =================== dense + softmax ===================
__global__ __launch_bounds__(64, 1)
void dense_softmax_kernel(const float* __restrict__ h2, const float* __restrict__ Wd,
                          const float* __restrict__ bd, float* __restrict__ out)
{
    const int b = blockIdx.x;
    const int k = threadIdx.x;
    __shared__ __align__(16) float hsm[H2];
    if (k < H2 / 4) ((f4v*)hsm)[k] = ((const f4v*)(h2 + (size_t)b * H2))[k];
    __syncthreads();

    float logit = -1e30f;
    if (k < NCLS) {
        float acc = bd[k];
#pragma unroll
        for (int d = 0; d < H2; ++d) acc += hsm[d] * Wd[d * NCLS + k];
        logit = acc;
    }
    float m = logit;
#pragma unroll
    for (int off = 32; off >= 1; off >>= 1) m = fmaxf(m, __shfl_xor(m, off, 64));
    float e = (k < NCLS) ? __expf(logit - m) : 0.0f;
    float s = e;
#pragma unroll
    for (int off = 32; off >= 1; off >>= 1) s += __shfl_xor(s, off, 64);
    if (k < NCLS) out[(size_t)b * NCLS + k] = e / s;
}

// =================== fallback (round-1) kernels ===================
__global__ __launch_bounds__(448, 1)
void lstm1_fb(const float* __restrict__ x, const float* __restrict__ W1,
              const float* __restrict__ U1, const float* __restrict__ b1,
              float* __restrict__ h1out)
{
    const int b = blockIdx.x;
    const int k = threadIdx.x;
    __shared__ __align__(16) float xs[IN_DIM];
    __shared__ __align__(16) float hs[H1];
    __shared__ __align__(16) float zs[4 * H1];
    float w1r[IN_DIM];
    float u1r[H1];
    float bias = 0.0f;
    if (k < 4 * H1) {
        bias = b1[k];
#pragma unroll
        for (int d = 0; d < IN_DIM; ++d) w1r[d] = W1[d * (4 * H1) + k];
#pragma unroll
        for (int j = 0; j < H1; ++j) u1r[j] = U1[j * (4 * H1) + k];
    }
    if (k < H1) hs[k] = 0.0f;
    if (k < IN_DIM / 4)
        ((float4*)xs)[k] = ((const float4*)(x + ((size_t)b * T_SEQ) * IN_DIM))[k];
    float c = 0.0f;
    __syncthreads();
    for (int t = 0; t < T_SEQ; ++t) {
        if (k < 4 * H1) {
            float acc0 = bias, acc1 = 0.f, acc2 = 0.f, acc3 = 0.f;
#pragma unroll
            for (int q = 0; q < IN_DIM / 4; ++q) {
                float4 xv = ((const float4*)xs)[q];
                acc0 += xv.x * w1r[4 * q]; acc1 += xv.y * w1r[4 * q + 1];
                acc2 += xv.z * w1r[4 * q + 2]; acc3 += xv.w * w1r[4 * q + 3];
            }
#pragma unroll
            for (int q = 0; q < H1 / 4; ++q) {
                float4 hv = ((const float4*)hs)[q];
                acc0 += hv.x * u1r[4 * q]; acc1 += hv.y * u1r[4 * q + 1];
                acc2 += hv.z * u1r[4 * q + 2]; acc3 += hv.w * u1r[4 * q + 3];
            }
            float zv = (acc0 + acc1) + (acc2 + acc3);
            zs[k] = (k >= 2 * H1 && k < 3 * H1) ? fmaxf(zv, 0.0f) : sigmoidf_(zv);
        }
        __syncthreads();
        if (k < H1) {
            float i = zs[k], f = zs[k + H1], g = zs[k + 2 * H1], o = zs[k + 3 * H1];
            c = f * c + i * g;
            float h = o * fmaxf(c, 0.0f);
            hs[k] = h;
            h1out[((size_t)t * BATCH + b) * H1 + k] = h;
        }
        int tn = t + 1;
        if (tn < T_SEQ && k < IN_DIM / 4)
            ((float4*)xs)[k] = ((const float4*)(x + ((size_t)b * T_SEQ + tn) * IN_DIM))[k];
        __syncthreads();
    }
}

__global__ __launch_bounds__(512, 1)
void lstm2_fb(const float* __restrict__ h1in, const float* __restrict__ W2,
              const float* __restrict__ U2, const float* __restrict__ b2,
              float* __restrict__ h2out)
{
    const int b = blockIdx.x;
    const int k = threadIdx.x;
    __shared__ __align__(16) float ps[H1];
    __shared__ __align__(16) float hs[H2];
    __shared__ __align__(16) float zs[4 * H2];
    float w2r[H1];
    float u2r[H2];
    float bias = b2[k];
#pragma unroll
    for (int j = 0; j < H1; ++j) w2r[j] = W2[j * (4 * H2) + k];
#pragma unroll
    for (int j = 0; j < H2; ++j) u2r[j] = U2[j * (4 * H2) + k];
    if (k < H2) hs[k] = 0.0f;
    if (k < H1 / 4)
        ((float4*)ps)[k] = ((const float4*)(h1in + (size_t)b * H1))[k];
    float c = 0.0f;
    float hlast = 0.0f;
    __syncthreads();
    for (int t = 0; t < T_SEQ; ++t) {
        float acc0 = bias, acc1 = 0.f, acc2 = 0.f, acc3 = 0.f;
#pragma unroll
        for (int q = 0; q < H1 / 4; ++q) {
            float4 pv = ((const float4*)ps)[q];
            acc0 += pv.x * w2r[4 * q]; acc1 += pv.y * w2r[4 * q + 1];
            acc2 += pv.z * w2r[4 * q + 2]; acc3 += pv.w * w2r[4 * q + 3];
        }
#pragma unroll
        for (int q = 0; q < H2 / 4; ++q) {
            float4 hv = ((const float4*)hs)[q];
            acc0 += hv.x * u2r[4 * q]; acc1 += hv.y * u2r[4 * q + 1];
            acc2 += hv.z * u2r[4 * q + 2]; acc3 += hv.w * u2r[4 * q + 3];
        }
        float zv = (acc0 + acc1) + (acc2 + acc3);
        zs[k] = (k >= 2 * H2 && k < 3 * H2) ? fmaxf(zv, 0.0f) : sigmoidf_(zv);
        __syncthreads();
        if (k < H2) {
            float i = zs[k], f = zs[k + H2], g = zs[k + 2 * H2], o = zs[k + 3 * H2];
            c = f * c + i * g;
            hlast = o * fmaxf(c, 0.0f);
            hs[k] = hlast;
        }
        int tn = t + 1;
        if (tn < T_SEQ && k < H1 / 4)
            ((float4*)ps)[k] = ((const float4*)(h1in + ((size_t)tn * BATCH + b) * H1))[k];
        __syncthreads();
    }
    if (k < H2) h2out[(size_t)b * H2 + k] = hlast;
}

extern "C" void kernel_launch(void* const* d_in, const int* in_sizes, int n_in,
                              void* d_out, int out_size, void* d_ws, size_t ws_size,
                              hipStream_t stream) {
    const float* x  = (const float*)d_in[0];
    const float* W1 = (const float*)d_in[1];
    const float* U1 = (const float*)d_in[2];
    const float* b1 = (const float*)d_in[3];
    const float* W2 = (const float*)d_in[4];
    const float* U2 = (const float*)d_in[5];
    const float* b2 = (const float*)d_in[6];
    const float* Wd = (const float*)d_in[7];
    const float* bd = (const float*)d_in[8];
    float* out = (float*)d_out;

    const size_t zx_elems = (size_t)T_SEQ * BATCH * 400;   // 52428800
    const size_t h1_elems = (size_t)T_SEQ * BATCH * H1;    // 13107200
    const size_t st_elems = (size_t)BATCH * H2;            // 65536
    const size_t need = (zx_elems + h1_elems + 3 * st_elems) * sizeof(float);  // 262.93 MB

    if (ws_size >= need) {
        float* zxbuf = (float*)d_ws;
        float* h1buf = zxbuf + zx_elems;
        float* cbuf  = h1buf + h1_elems;
        float* hbuf  = cbuf + st_elems;
        float* h2buf = hbuf + st_elems;
        const int TC = T_SEQ / 2;   // 128-step chunks

        // zx1 = x @ W1 + b1 -> [T][B][400]
        hipLaunchKernelGGL((proj_kernel<IN_DIM, 4 * H1, true>), dim3(1024, 4), dim3(256), 0, stream,
                           x, W1, b1, zxbuf);
        // rec1: MFMA recurrence, full 256 steps, h1seq out
        hipLaunchKernelGGL((recm_kernel<H1, true, true, false, false>), dim3(32), dim3(256), 0, stream,
                           zxbuf, U1, h1buf, (float*)nullptr, (float*)nullptr, T_SEQ);
        // ---- layer 2, chunk A (t = 0..127) ----
        hipLaunchKernelGGL((proj_kernel<H1, 4 * H2, false>), dim3(512, 4), dim3(256), 0, stream,
                           h1buf, W2, b2, zxbuf);
        hipLaunchKernelGGL((recm_kernel<H2, false, true, true, false>), dim3(32), dim3(256), 0, stream,
                           zxbuf, U2, (float*)nullptr, cbuf, hbuf, TC);
        // ---- layer 2, chunk B (t = 128..255) ----
        hipLaunchKernelGGL((proj_kernel<H1, 4 * H2, false>), dim3(512, 4), dim3(256), 0, stream,
                           h1buf + (size_t)TC * BATCH * H1, W2, b2, zxbuf);
        hipLaunchKernelGGL((recm_kernel<H2, false, false, false, true>), dim3(32), dim3(256), 0, stream,
                           zxbuf, U2, h2buf, cbuf, hbuf, TC);

        hipLaunchKernelGGL(dense_softmax_kernel, dim3(BATCH), dim3(64), 0, stream,
                           h2buf, Wd, bd, out);
    } else {
        // fallback: round-1 fused kernels (needs ~52.7 MB)
        float* h1buf = (float*)d_ws;
        float* h2buf = h1buf + h1_elems;
        hipLaunchKernelGGL(lstm1_fb, dim3(BATCH), dim3(448), 0, stream, x, W1, U1, b1, h1buf);
        hipLaunchKernelGGL(lstm2_fb, dim3(BATCH), dim3(512), 0, stream, h1buf, W2, U2, b2, h2buf);
        hipLaunchKernelGGL(dense_softmax_kernel, dim3(BATCH), dim3(64), 0, stream, h2buf, Wd, bd, out);
    }
}

// Round 7
// 1788.704 us; speedup vs baseline: 1.3959x; 1.3959x over previous
//
#include <hip/hip_runtime.h>
#include <math.h>

// TfLSTM: x[512,256,128] -> LSTM(100, relu) -> LSTM(128, relu, last) -> Dense(19) -> softmax
// Round 7: in-register-gate MFMA recurrence. Wave w owns unit groups {2w,2w+1};
// tiles {g, g+8, g+16, g+24} put all 4 gates of a unit in the SAME lane's
// C-regs -> gate/c/h update fully in registers (r6's za LDS funnel deleted).
// zx register-prefetched one step ahead (r6's exposed global latency fixed).
// hA double-buffered -> ONE barrier/step. Layer 1 padded NU=100->128 via
// proj1p writing gate-padded zx [tl][B][512] (pad cols == 0 -> padded units
// provably stay h=c=0). Both layers chunked 2x128 steps (zx chunk 134 MB).
//   ws: zxbuf 134.2MB | h1seq 52.4MB | 5 state bufs 0.26MB ea  = 188MB < 256MiB

#define T_SEQ 256
#define BATCH 512
#define IN_DIM 128
#define H1 100
#define H2 128
#define NCLS 19

typedef float f4v __attribute__((ext_vector_type(4)));
typedef short s8v __attribute__((ext_vector_type(8)));

#define ZERO8 ((s8v){0, 0, 0, 0, 0, 0, 0, 0})
// slots: (group-sel g in {0,1}) x (gate ga in {0..3})
#define FOR_SLOT(M) M(0,0) M(0,1) M(0,2) M(0,3) M(1,0) M(1,1) M(1,2) M(1,3)

__device__ __forceinline__ float sigmoidf_(float x) {
    return 1.0f / (1.0f + __expf(-x));
}
__device__ __forceinline__ f4v sig4_(f4v z) {
    f4v r;
    r.x = sigmoidf_(z.x); r.y = sigmoidf_(z.y);
    r.z = sigmoidf_(z.z); r.w = sigmoidf_(z.w);
    return r;
}
__device__ __forceinline__ f4v relu4_(f4v z) {
    f4v r;
    r.x = fmaxf(z.x, 0.f); r.y = fmaxf(z.y, 0.f);
    r.z = fmaxf(z.z, 0.f); r.w = fmaxf(z.w, 0.f);
    return r;
}
// RNE fp32->bf16 + exact hi float
__device__ __forceinline__ short bf_hi_(float x, float& hif) {
    unsigned u = __builtin_bit_cast(unsigned, x);
    unsigned r = (u + 0x7FFFu + ((u >> 16) & 1u)) & 0xFFFF0000u;
    hif = __builtin_bit_cast(float, r);
    return (short)(r >> 16);
}
__device__ __forceinline__ void bsplit_(float x, short& hi, short& lo) {
    float hif;
    hi = bf_hi_(x, hif);
    float rs = x - hif;
    float d;
    lo = bf_hi_(rs, d);
}
// A-frag: 8 consecutive fp32 from LDS -> hi/lo bf16 (element-wise, no alloca)
__device__ __forceinline__ void load_af_(const float* p, s8v& ah, s8v& al) {
    f4v x0 = *(const f4v*)p;
    f4v x1 = *(const f4v*)(p + 4);
    short h, l;
    bsplit_(x0.x, h, l); ah[0] = h; al[0] = l;
    bsplit_(x0.y, h, l); ah[1] = h; al[1] = l;
    bsplit_(x0.z, h, l); ah[2] = h; al[2] = l;
    bsplit_(x0.w, h, l); ah[3] = h; al[3] = l;
    bsplit_(x1.x, h, l); ah[4] = h; al[4] = l;
    bsplit_(x1.y, h, l); ah[5] = h; al[5] = l;
    bsplit_(x1.z, h, l); ah[6] = h; al[6] = l;
    bsplit_(x1.w, h, l); ah[7] = h; al[7] = l;
}
// B-frag: B[k = kt*32+lq*8+j][col' = ga*128+u]; PAD remaps into U1[100][400].
template<bool PAD>
__device__ __forceinline__ void load_bf_(const float* __restrict__ U,
                                         int u, int ga, int kt, int lq,
                                         s8v& hi, s8v& lo) {
    short h, l;
#pragma unroll
    for (int j = 0; j < 8; ++j) {
        int k = kt * 32 + lq * 8 + j;
        float x;
        if (PAD) x = (u < 100 && k < 100) ? U[(size_t)k * 400 + ga * 100 + u] : 0.0f;
        else     x = U[(size_t)k * 512 + ga * 128 + u];
        bsplit_(x, h, l);
        hi[j] = h; lo[j] = l;
    }
}

// =================== in-register-gate MFMA recurrence ===================
// Block: 16 batch rows, 256 threads (4 waves), grid 32. NU=128 (PAD: 100 real).
template<bool PAD, bool SEQOUT, bool INIT, bool WROUT>
__global__ __launch_bounds__(256)
__attribute__((amdgpu_waves_per_eu(1, 1)))
void recg_kernel(const float* __restrict__ zx,    // [tlen][B][512] (bias incl)
                 const float* __restrict__ U,     // PAD ? [100][400] : [128][512]
                 float* __restrict__ outp,        // SEQOUT: h1seq(+t0) [t][B][100]; WROUT: h2 [B][128]
                 float* __restrict__ cbuf,        // [B][128] c carry
                 float* __restrict__ hbuf,        // [B][128] h carry
                 int tlen)
{
    constexpr int ALD = 132;           // 128 + 4 pad (2-way b128 phases)
    constexpr int HB = 16 * ALD;       // one hA buffer
    __shared__ __align__(16) float hA[2 * HB];

    const int tid = threadIdx.x;
    const int wv = tid >> 6;
    const int lane = tid & 63;
    const int lm = lane & 15;
    const int lq = lane >> 4;
    const int blk16 = blockIdx.x * 16;

    // ---- one-time B-frag load: 8 slots x 4 ktiles x hi/lo (256 VGPRs) ----
#define BDECL(g, ga) \
    s8v bh##g##ga##_0, bl##g##ga##_0, bh##g##ga##_1, bl##g##ga##_1, \
        bh##g##ga##_2, bl##g##ga##_2, bh##g##ga##_3, bl##g##ga##_3; \
    { int u = 32 * wv + 16 * (g) + lm; \
      load_bf_<PAD>(U, u, ga, 0, lq, bh##g##ga##_0, bl##g##ga##_0); \
      load_bf_<PAD>(U, u, ga, 1, lq, bh##g##ga##_1, bl##g##ga##_1); \
      load_bf_<PAD>(U, u, ga, 2, lq, bh##g##ga##_2, bl##g##ga##_2); \
      load_bf_<PAD>(U, u, ga, 3, lq, bh##g##ga##_3, bl##g##ga##_3); }
    FOR_SLOT(BDECL)
#undef BDECL

    // ---- init h(0) into hA[0] ----
    if (INIT) {
        for (int i = tid; i < HB; i += 256) hA[i] = 0.0f;
    } else {
        int row = tid >> 4, k8 = (tid & 15) * 8;
        f4v a = *(const f4v*)&hbuf[(size_t)(blk16 + row) * 128 + k8];
        f4v b = *(const f4v*)&hbuf[(size_t)(blk16 + row) * 128 + k8 + 4];
        *(f4v*)&hA[row * ALD + k8] = a;
        *(f4v*)&hA[row * ALD + k8 + 4] = b;
    }
    // ---- c state (C-layout: rows lq*4+r, col u) ----
    f4v c0r = {0.f, 0.f, 0.f, 0.f}, c1r = {0.f, 0.f, 0.f, 0.f};
    if (!INIT) {
#define CG(g, dst) { int u = 32 * wv + 16 * (g) + lm; \
        const float* pc = cbuf + ((size_t)(blk16 + lq * 4)) * 128 + u; \
        dst = (f4v){pc[0], pc[128], pc[256], pc[384]}; }
        CG(0, c0r) CG(1, c1r)
#undef CG
    }
    // ---- zc = zx(t=0) ----
#define ZDECL(g, ga) f4v zc##g##ga, zn##g##ga;
    FOR_SLOT(ZDECL)
#undef ZDECL
#define ZLD(g, ga, tt, dst) { \
    const float* p = zx + ((size_t)(tt) * BATCH + blk16 + lq * 4) * 512 \
                     + (ga) * 128 + 32 * wv + 16 * (g) + lm; \
    dst##g##ga = (f4v){p[0], p[512], p[1024], p[1536]}; }
#define Z0(g, ga) ZLD(g, ga, 0, zc)
    FOR_SLOT(Z0)
#undef Z0
    __syncthreads();

#define MT(g, ga, kt) \
    ac##g##ga = __builtin_amdgcn_mfma_f32_16x16x32_bf16(ah##kt, bh##g##ga##_##kt, ac##g##ga, 0, 0, 0); \
    ac##g##ga = __builtin_amdgcn_mfma_f32_16x16x32_bf16(al##kt, bh##g##ga##_##kt, ac##g##ga, 0, 0, 0); \
    ac##g##ga = __builtin_amdgcn_mfma_f32_16x16x32_bf16(ah##kt, bl##g##ga##_##kt, ac##g##ga, 0, 0, 0);
#define SLOTM(g, ga) f4v ac##g##ga = zc##g##ga; MT(g, ga, 0) MT(g, ga, 1) MT(g, ga, 2) MT(g, ga, 3)
#define ZN(g, ga) ZLD(g, ga, tn, zn)
#define ZMOV(g, ga) zc##g##ga = zn##g##ga;
#define GRP(g, cr) { \
    f4v iv = sig4_(ac##g##0); f4v fv = sig4_(ac##g##1); \
    f4v gv = relu4_(ac##g##2); f4v ov = sig4_(ac##g##3); \
    cr = fv * cr + iv * gv; \
    f4v hv = ov * relu4_(cr); \
    int u = 32 * wv + 16 * (g) + lm; \
    hn[(lq * 4 + 0) * ALD + u] = hv.x; \
    hn[(lq * 4 + 1) * ALD + u] = hv.y; \
    hn[(lq * 4 + 2) * ALD + u] = hv.z; \
    hn[(lq * 4 + 3) * ALD + u] = hv.w; \
    if (SEQOUT) { \
        if (!PAD || u < 100) { \
            float* po = outp + ((size_t)t * BATCH + blk16 + lq * 4) * 100 + u; \
            po[0] = hv.x; po[100] = hv.y; po[200] = hv.z; po[300] = hv.w; \
        } \
    } }

#pragma unroll 1
    for (int t = 0; t < tlen; ++t) {
        const float* hc = hA + (t & 1) * HB;
        float* hn = hA + ((t + 1) & 1) * HB;
        // A-frags from current h
        s8v ah0, al0, ah1, al1, ah2, al2, ah3, al3;
        load_af_(hc + lm * ALD +  0 + lq * 8, ah0, al0);
        load_af_(hc + lm * ALD + 32 + lq * 8, ah1, al1);
        load_af_(hc + lm * ALD + 64 + lq * 8, ah2, al2);
        load_af_(hc + lm * ALD + 96 + lq * 8, ah3, al3);
        // prefetch z(t+1)
        int tn = (t + 1 < tlen) ? t + 1 : t;
        FOR_SLOT(ZN)
        // MFMA all 8 tiles (acc init = zx)
        FOR_SLOT(SLOTM)
        // in-register gates + c/h update + h broadcast write
        GRP(0, c0r) GRP(1, c1r)
        __syncthreads();
        FOR_SLOT(ZMOV)
    }
#undef MT
#undef SLOTM
#undef ZN
#undef ZMOV
#undef GRP
#undef ZLD

    // ---- chunk carry + outputs ----
    const float* hf = hA + (tlen & 1) * HB;
    {
        int row = tid >> 4, k8 = (tid & 15) * 8;
        f4v a = *(const f4v*)&hf[row * ALD + k8];
        f4v b = *(const f4v*)&hf[row * ALD + k8 + 4];
        *(f4v*)&hbuf[(size_t)(blk16 + row) * 128 + k8] = a;
        *(f4v*)&hbuf[(size_t)(blk16 + row) * 128 + k8 + 4] = b;
        if (WROUT) {
            *(f4v*)&outp[(size_t)(blk16 + row) * 128 + k8] = a;
            *(f4v*)&outp[(size_t)(blk16 + row) * 128 + k8 + 4] = b;
        }
    }
#define CS(g, src) { int u = 32 * wv + 16 * (g) + lm; \
    float* pc = cbuf + ((size_t)(blk16 + lq * 4)) * 128 + u; \
    pc[0] = src.x; pc[128] = src.y; pc[256] = src.z; pc[384] = src.w; }
    CS(0, c0r) CS(1, c1r)
#undef CS
}

// =================== layer-1 projection, gate-padded output ===================
// zx1[tl][B][512]: col' = gate*128+u  <- x@W1+b1 cols gate*100+u (u<100), else 0.
// Block: batch row b = blockIdx.x (128 t-rows), cols c0 = blockIdx.y*128.
__global__ __launch_bounds__(256, 2)
void proj1p_kernel(const float* __restrict__ x, const float* __restrict__ W1,
                   const float* __restrict__ b1, float* __restrict__ out, int t0)
{
    constexpr int LD = 132;
    __shared__ __align__(16) float As[32 * LD];
    __shared__ __align__(16) float Ws[32 * LD];
    const int tid = threadIdx.x;
    const int b = blockIdx.x;
    const int c0 = blockIdx.y * 128;
    const int ty = tid >> 4, tx = tid & 15;
    const float* A = x + ((size_t)b * T_SEQ + t0) * IN_DIM;

#define PACC(i) f4v accL##i = {0.f,0.f,0.f,0.f}; f4v accR##i = {0.f,0.f,0.f,0.f};
    PACC(0) PACC(1) PACC(2) PACC(3) PACC(4) PACC(5) PACC(6) PACC(7)
#undef PACC

    for (int kk = 0; kk < IN_DIM; kk += 32) {
        __syncthreads();
#pragma unroll
        for (int i = 0; i < 4; ++i) {
            int idx = tid + i * 256;
            int row = idx >> 3, kg = idx & 7;
            int k = kk + kg * 4;
            f4v v = *(const f4v*)&A[(size_t)row * IN_DIM + k];
            As[(kg * 4 + 0) * LD + row] = v.x;
            As[(kg * 4 + 1) * LD + row] = v.y;
            As[(kg * 4 + 2) * LD + row] = v.z;
            As[(kg * 4 + 3) * LD + row] = v.w;
        }
#pragma unroll
        for (int i = 0; i < 4; ++i) {
            int idx = tid + i * 256;
            int k = idx >> 5, cg = idx & 31;
            int gk = kk + k;
            int gcp = c0 + cg * 4;
            int gate = gcp >> 7, ub = gcp & 127;
            f4v v;
            v.x = (ub + 0 < 100) ? W1[(size_t)gk * 400 + gate * 100 + ub + 0] : 0.f;
            v.y = (ub + 1 < 100) ? W1[(size_t)gk * 400 + gate * 100 + ub + 1] : 0.f;
            v.z = (ub + 2 < 100) ? W1[(size_t)gk * 400 + gate * 100 + ub + 2] : 0.f;
            v.w = (ub + 3 < 100) ? W1[(size_t)gk * 400 + gate * 100 + ub + 3] : 0.f;
            *(f4v*)&Ws[k * LD + cg * 4] = v;
        }
        __syncthreads();
#pragma unroll
        for (int k = 0; k < 32; ++k) {
            f4v av0 = *(const f4v*)&As[k * LD + ty * 8];
            f4v av1 = *(const f4v*)&As[k * LD + ty * 8 + 4];
            f4v b0v = *(const f4v*)&Ws[k * LD + tx * 8];
            f4v b1v = *(const f4v*)&Ws[k * LD + tx * 8 + 4];
#define PFMA(i, s) accL##i += (s) * b0v; accR##i += (s) * b1v;
            PFMA(0, av0.x) PFMA(1, av0.y) PFMA(2, av0.z) PFMA(3, av0.w)
            PFMA(4, av1.x) PFMA(5, av1.y) PFMA(6, av1.z) PFMA(7, av1.w)
#undef PFMA
        }
    }

    const int cb = c0 + tx * 8;
    f4v bL, bR;
#pragma unroll
    for (int j = 0; j < 4; ++j) {
        int gate = (cb + j) >> 7, u = (cb + j) & 127;
        bL[j] = (u < 100) ? b1[gate * 100 + u] : 0.f;
    }
#pragma unroll
    for (int j = 0; j < 4; ++j) {
        int gate = (cb + 4 + j) >> 7, u = (cb + 4 + j) & 127;
        bR[j] = (u < 100) ? b1[gate * 100 + u] : 0.f;
    }
#define PST(i) { \
        int tl = ty * 8 + i; \
        size_t orow = (size_t)tl * BATCH + b; \
        f4v vL = accL##i + bL; *(f4v*)&out[orow * 512 + cb] = vL; \
        f4v vR = accR##i + bR; *(f4v*)&out[orow * 512 + cb + 4] = vR; }
    PST(0) PST(1) PST(2) PST(3) PST(4) PST(5) PST(6) PST(7)
#undef PST
}

// =================== generic projection GEMM (r5, for layer 2) ===================
#define PREP8(M)  M(0) M(1) M(2) M(3) M(4) M(5) M(6) M(7)
template<int K, int N, bool SWAP>
__global__ __launch_bounds__(256, 2)
void proj_kernel(const float* __restrict__ A, const float* __restrict__ W,
                 const float* __restrict__ bias, float* __restrict__ out)
{
    constexpr int LD = 132;
    __shared__ __align__(16) float As[32 * LD];
    __shared__ __align__(16) float Ws[32 * LD];
    const int tid = threadIdx.x;
    const int r0 = blockIdx.x * 128;
    const int c0 = blockIdx.y * 128;
    const int ty = tid >> 4, tx = tid & 15;

#define PACC(i) f4v accL##i = {0.f,0.f,0.f,0.f}; f4v accR##i = {0.f,0.f,0.f,0.f};
    PREP8(PACC)
#undef PACC

    for (int kk = 0; kk < K; kk += 32) {
        __syncthreads();
#pragma unroll
        for (int i = 0; i < 4; ++i) {
            int idx = tid + i * 256;
            int row = idx >> 3, kg = idx & 7;
            int k = kk + kg * 4;
            f4v v = {0.f, 0.f, 0.f, 0.f};
            if (k < K) v = *(const f4v*)&A[(size_t)(r0 + row) * K + k];
            As[(kg * 4 + 0) * LD + row] = v.x;
            As[(kg * 4 + 1) * LD + row] = v.y;
            As[(kg * 4 + 2) * LD + row] = v.z;
            As[(kg * 4 + 3) * LD + row] = v.w;
        }
#pragma unroll
        for (int i = 0; i < 4; ++i) {
            int idx = tid + i * 256;
            int k = idx >> 5, cg = idx & 31;
            int gk = kk + k, gc = c0 + cg * 4;
            f4v v = {0.f, 0.f, 0.f, 0.f};
            if (gk < K && gc < N) v = *(const f4v*)&W[(size_t)gk * N + gc];
            *(f4v*)&Ws[k * LD + cg * 4] = v;
        }
        __syncthreads();
#pragma unroll
        for (int k = 0; k < 32; ++k) {
            f4v av0 = *(const f4v*)&As[k * LD + ty * 8];
            f4v av1 = *(const f4v*)&As[k * LD + ty * 8 + 4];
            f4v b0v = *(const f4v*)&Ws[k * LD + tx * 8];
            f4v b1v = *(const f4v*)&Ws[k * LD + tx * 8 + 4];
#define PFMA(i, s) accL##i += (s) * b0v; accR##i += (s) * b1v;
            PFMA(0, av0.x) PFMA(1, av0.y) PFMA(2, av0.z) PFMA(3, av0.w)
            PFMA(4, av1.x) PFMA(5, av1.y) PFMA(6, av1.z) PFMA(7, av1.w)
#undef PFMA
        }
    }

    const int cb = c0 + tx * 8;
    f4v bL, bR;
#pragma unroll
    for (int j = 0; j < 4; ++j) bL[j] = (cb + j < N) ? bias[cb + j] : 0.f;
#pragma unroll
    for (int j = 0; j < 4; ++j) bR[j] = (cb + 4 + j < N) ? bias[cb + 4 + j] : 0.f;
#define PST(i) { \
        int r = r0 + ty * 8 + i; \
        size_t orow = SWAP ? ((size_t)(r & 255) * BATCH + (r >> 8)) : (size_t)r; \
        if (cb < N)     { f4v v = accL##i + bL; *(f4v*)&out[orow * N + cb] = v; } \
        if (cb + 4 < N) { f4v v = accR##i + bR; *(f4v*)&out[orow * N + cb + 4] = v; } }
    PREP8(PST)
#undef PST
}

// =================== dense + softmax ===================
__global__ __launch_bounds__(64, 1)
void dense_softmax_kernel(const float* __restrict__ h2, const float* __restrict__ Wd,
                          const float* __restrict__ bd, float* __restrict__ out)
{
    const int b = blockIdx.x;
    const int k = threadIdx.x;
    __shared__ __align__(16) float hsm[H2];
    if (k < H2 / 4) ((f4v*)hsm)[k] = ((const f4v*)(h2 + (size_t)b * H2))[k];
    __syncthreads();

    float logit = -1e30f;
    if (k < NCLS) {
        float acc = bd[k];
#pragma unroll
        for (int d = 0; d < H2; ++d) acc += hsm[d] * Wd[d * NCLS + k];
        logit = acc;
    }
    float m = logit;
#pragma unroll
    for (int off = 32; off >= 1; off >>= 1) m = fmaxf(m, __shfl_xor(m, off, 64));
    float e = (k < NCLS) ? __expf(logit - m) : 0.0f;
    float s = e;
#pragma unroll
    for (int off = 32; off >= 1; off >>= 1) s += __shfl_xor(s, off, 64);
    if (k < NCLS) out[(size_t)b * NCLS + k] = e / s;
}

// =================== fallback (round-1) kernels ===================
__global__ __launch_bounds__(448, 1)
void lstm1_fb(const float* __restrict__ x, const float* __restrict__ W1,
              const float* __restrict__ U1, const float* __restrict__ b1,
              float* __restrict__ h1out)
{
    const int b = blockIdx.x;
    const int k = threadIdx.x;
    __shared__ __align__(16) float xs[IN_DIM];
    __shared__ __align__(16) float hs[H1];
    __shared__ __align__(16) float zs[4 * H1];
    float w1r[IN_DIM];
    float u1r[H1];
    float bias = 0.0f;
    if (k < 4 * H1) {
        bias = b1[k];
#pragma unroll
        for (int d = 0; d < IN_DIM; ++d) w1r[d] = W1[d * (4 * H1) + k];
#pragma unroll
        for (int j = 0; j < H1; ++j) u1r[j] = U1[j * (4 * H1) + k];
    }
    if (k < H1) hs[k] = 0.0f;
    if (k < IN_DIM / 4)
        ((float4*)xs)[k] = ((const float4*)(x + ((size_t)b * T_SEQ) * IN_DIM))[k];
    float c = 0.0f;
    __syncthreads();
    for (int t = 0; t < T_SEQ; ++t) {
        if (k < 4 * H1) {
            float acc0 = bias, acc1 = 0.f, acc2 = 0.f, acc3 = 0.f;
#pragma unroll
            for (int q = 0; q < IN_DIM / 4; ++q) {
                float4 xv = ((const float4*)xs)[q];
                acc0 += xv.x * w1r[4 * q]; acc1 += xv.y * w1r[4 * q + 1];
                acc2 += xv.z * w1r[4 * q + 2]; acc3 += xv.w * w1r[4 * q + 3];
            }
#pragma unroll
            for (int q = 0; q < H1 / 4; ++q) {
                float4 hv = ((const float4*)hs)[q];
                acc0 += hv.x * u1r[4 * q]; acc1 += hv.y * u1r[4 * q + 1];
                acc2 += hv.z * u1r[4 * q + 2]; acc3 += hv.w * u1r[4 * q + 3];
            }
            float zv = (acc0 + acc1) + (acc2 + acc3);
            zs[k] = (k >= 2 * H1 && k < 3 * H1) ? fmaxf(zv, 0.0f) : sigmoidf_(zv);
        }
        __syncthreads();
        if (k < H1) {
            float i = zs[k], f = zs[k + H1], g = zs[k + 2 * H1], o = zs[k + 3 * H1];
            c = f * c + i * g;
            float h = o * fmaxf(c, 0.0f);
            hs[k] = h;
            h1out[((size_t)t * BATCH + b) * H1 + k] = h;
        }
        int tn = t + 1;
        if (tn < T_SEQ && k < IN_DIM / 4)
            ((float4*)xs)[k] = ((const float4*)(x + ((size_t)b * T_SEQ + tn) * IN_DIM))[k];
        __syncthreads();
    }
}

__global__ __launch_bounds__(512, 1)
void lstm2_fb(const float* __restrict__ h1in, const float* __restrict__ W2,
              const float* __restrict__ U2, const float* __restrict__ b2,
              float* __restrict__ h2out)
{
    const int b = blockIdx.x;
    const int k = threadIdx.x;
    __shared__ __align__(16) float ps[H1];
    __shared__ __align__(16) float hs[H2];
    __shared__ __align__(16) float zs[4 * H2];
    float w2r[H1];
    float u2r[H2];
    float bias = b2[k];
#pragma unroll
    for (int j = 0; j < H1; ++j) w2r[j] = W2[j * (4 * H2) + k];
#pragma unroll
    for (int j = 0; j < H2; ++j) u2r[j] = U2[j * (4 * H2) + k];
    if (k < H2) hs[k] = 0.0f;
    if (k < H1 / 4)
        ((float4*)ps)[k] = ((const float4*)(h1in + (size_t)b * H1))[k];
    float c = 0.0f;
    float hlast = 0.0f;
    __syncthreads();
    for (int t = 0; t < T_SEQ; ++t) {
        float acc0 = bias, acc1 = 0.f, acc2 = 0.f, acc3 = 0.f;
#pragma unroll
        for (int q = 0; q < H1 / 4; ++q) {
            float4 pv = ((const float4*)ps)[q];
            acc0 += pv.x * w2r[4 * q]; acc1 += pv.y * w2r[4 * q + 1];
            acc2 += pv.z * w2r[4 * q + 2]; acc3 += pv.w * w2r[4 * q + 3];
        }
#pragma unroll
        for (int q = 0; q < H2 / 4; ++q) {
            float4 hv = ((const float4*)hs)[q];
            acc0 += hv.x * u2r[4 * q]; acc1 += hv.y * u2r[4 * q + 1];
            acc2 += hv.z * u2r[4 * q + 2]; acc3 += hv.w * u2r[4 * q + 3];
        }
        float zv = (acc0 + acc1) + (acc2 + acc3);
        zs[k] = (k >= 2 * H2 && k < 3 * H2) ? fmaxf(zv, 0.0f) : sigmoidf_(zv);
        __syncthreads();
        if (k < H2) {
            float i = zs[k], f = zs[k + H2], g = zs[k + 2 * H2], o = zs[k + 3 * H2];
            c = f * c + i * g;
            hlast = o * fmaxf(c, 0.0f);
            hs[k] = hlast;
        }
        int tn = t + 1;
        if (tn < T_SEQ && k < H1 / 4)
            ((float4*)ps)[k] = ((const float4*)(h1in + ((size_t)tn * BATCH + b) * H1))[k];
        __syncthreads();
    }
    if (k < H2) h2out[(size_t)b * H2 + k] = hlast;
}

extern "C" void kernel_launch(void* const* d_in, const int* in_sizes, int n_in,
                              void* d_out, int out_size, void* d_ws, size_t ws_size,
                              hipStream_t stream) {
    const float* x  = (const float*)d_in[0];
    const float* W1 = (const float*)d_in[1];
    const float* U1 = (const float*)d_in[2];
    const float* b1 = (const float*)d_in[3];
    const float* W2 = (const float*)d_in[4];
    const float* U2 = (const float*)d_in[5];
    const float* b2 = (const float*)d_in[6];
    const float* Wd = (const float*)d_in[7];
    const float* bd = (const float*)d_in[8];
    float* out = (float*)d_out;

    const int TC = T_SEQ / 2;                                   // 128-step chunks
    const size_t zx_elems = (size_t)TC * BATCH * 512;           // 33554432 (134.2 MB)
    const size_t h1_elems = (size_t)T_SEQ * BATCH * H1;         // 13107200 (52.4 MB)
    const size_t st_elems = (size_t)BATCH * H2;                 // 65536
    const size_t need = (zx_elems + h1_elems + 5 * st_elems) * sizeof(float);  // ~188 MB

    if (ws_size >= need) {
        float* zxbuf = (float*)d_ws;
        float* h1buf = zxbuf + zx_elems;
        float* c1buf = h1buf + h1_elems;
        float* hc1buf = c1buf + st_elems;
        float* c2buf = hc1buf + st_elems;
        float* hc2buf = c2buf + st_elems;
        float* h2buf = hc2buf + st_elems;

        // ---- layer 1, chunk A (t 0..127) ----
        hipLaunchKernelGGL(proj1p_kernel, dim3(BATCH, 4), dim3(256), 0, stream,
                           x, W1, b1, zxbuf, 0);
        hipLaunchKernelGGL((recg_kernel<true, true, true, false>), dim3(32), dim3(256), 0, stream,
                           zxbuf, U1, h1buf, c1buf, hc1buf, TC);
        // ---- layer 1, chunk B (t 128..255) ----
        hipLaunchKernelGGL(proj1p_kernel, dim3(BATCH, 4), dim3(256), 0, stream,
                           x, W1, b1, zxbuf, TC);
        hipLaunchKernelGGL((recg_kernel<true, true, false, false>), dim3(32), dim3(256), 0, stream,
                           zxbuf, U1, h1buf + (size_t)TC * BATCH * H1, c1buf, hc1buf, TC);
        // ---- layer 2, chunk A ----
        hipLaunchKernelGGL((proj_kernel<H1, 4 * H2, false>), dim3(512, 4), dim3(256), 0, stream,
                           h1buf, W2, b2, zxbuf);
        hipLaunchKernelGGL((recg_kernel<false, false, true, false>), dim3(32), dim3(256), 0, stream,
                           zxbuf, U2, (float*)nullptr, c2buf, hc2buf, TC);
        // ---- layer 2, chunk B ----
        hipLaunchKernelGGL((proj_kernel<H1, 4 * H2, false>), dim3(512, 4), dim3(256), 0, stream,
                           h1buf + (size_t)TC * BATCH * H1, W2, b2, zxbuf);
        hipLaunchKernelGGL((recg_kernel<false, false, false, true>), dim3(32), dim3(256), 0, stream,
                           zxbuf, U2, h2buf, c2buf, hc2buf, TC);

        hipLaunchKernelGGL(dense_softmax_kernel, dim3(BATCH), dim3(64), 0, stream,
                           h2buf, Wd, bd, out);
    } else {
        // fallback: round-1 fused kernels (needs ~52.7 MB)
        float* h1buf = (float*)d_ws;
        float* h2buf = h1buf + h1_elems;
        hipLaunchKernelGGL(lstm1_fb, dim3(BATCH), dim3(448), 0, stream, x, W1, U1, b1, h1buf);
        hipLaunchKernelGGL(lstm2_fb, dim3(BATCH), dim3(512), 0, stream, h1buf, W2, U2, b2, h2buf);
        hipLaunchKernelGGL(dense_softmax_kernel, dim3(BATCH), dim3(64), 0, stream, h2buf, Wd, bd, out);
    }
}

// Round 8
// 1330.263 us; speedup vs baseline: 1.8770x; 1.3446x over previous
//
#include <hip/hip_runtime.h>
#include <math.h>

// TfLSTM: x[512,256,128] -> LSTM(100, relu) -> LSTM(128, relu, last) -> Dense(19) -> softmax
// Round 8: r7 in-register-gate MFMA recurrence, restructured for pressure+TLP:
//  - 512 threads (8 waves), wave w owns ONE unit-group (16 units, 4 gate slots)
//    -> B-frags 128 VGPRs/wave (r7: 256 -> AGPR shuffling, VGPR_Count=212)
//  - waves_per_eu(2,2): 256-reg budget, 2 waves/SIMD (r7 had 1 -> all latency exposed)
//  - h kept PRE-SPLIT (bf16 hi/lo) in LDS: A-frags ds_read_b128 directly,
//    deleting the per-step 32-value bsplit chain (~320 VALU cyc/wave)
//  - zn prefetch (16 regs only) issued at loop head, covered by MFMA+gate work
// Same split-bf16 triple product & fragment formulas as r7 (absmax 2.44e-4 verified).

#define T_SEQ 256
#define BATCH 512
#define IN_DIM 128
#define H1 100
#define H2 128
#define NCLS 19

typedef float f4v __attribute__((ext_vector_type(4)));
typedef short s8v __attribute__((ext_vector_type(8)));

#define FOR_GA(M) M(0) M(1) M(2) M(3)

__device__ __forceinline__ float sigmoidf_(float x) {
    return 1.0f / (1.0f + __expf(-x));
}
__device__ __forceinline__ f4v sig4_(f4v z) {
    f4v r;
    r.x = sigmoidf_(z.x); r.y = sigmoidf_(z.y);
    r.z = sigmoidf_(z.z); r.w = sigmoidf_(z.w);
    return r;
}
__device__ __forceinline__ f4v relu4_(f4v z) {
    f4v r;
    r.x = fmaxf(z.x, 0.f); r.y = fmaxf(z.y, 0.f);
    r.z = fmaxf(z.z, 0.f); r.w = fmaxf(z.w, 0.f);
    return r;
}
// RNE fp32->bf16 + exact hi float
__device__ __forceinline__ short bf_hi_(float x, float& hif) {
    unsigned u = __builtin_bit_cast(unsigned, x);
    unsigned r = (u + 0x7FFFu + ((u >> 16) & 1u)) & 0xFFFF0000u;
    hif = __builtin_bit_cast(float, r);
    return (short)(r >> 16);
}
__device__ __forceinline__ void bsplit_(float x, short& hi, short& lo) {
    float hif;
    hi = bf_hi_(x, hif);
    float rs = x - hif;
    float d;
    lo = bf_hi_(rs, d);
}
__device__ __forceinline__ float bf2f_(short s) {
    unsigned v = ((unsigned)(unsigned short)s) << 16;
    return __builtin_bit_cast(float, v);
}
// B-frag: B[k = kt*32+lq*8+j][col = ga*NU+u]; PAD remaps into U1[100][400].
template<bool PAD>
__device__ __forceinline__ void load_bf_(const float* __restrict__ U,
                                         int u, int ga, int kt, int lq,
                                         s8v& hi, s8v& lo) {
    short h, l;
#pragma unroll
    for (int j = 0; j < 8; ++j) {
        int k = kt * 32 + lq * 8 + j;
        float x;
        if (PAD) x = (u < 100 && k < 100) ? U[(size_t)k * 400 + ga * 100 + u] : 0.0f;
        else     x = U[(size_t)k * 512 + ga * 128 + u];
        bsplit_(x, h, l);
        hi[j] = h; lo[j] = l;
    }
}

// =================== in-register-gate MFMA recurrence (8-wave) ===================
// Block: 16 batch rows, 512 threads, grid 32. Wave w: units u = 16w+lm, 4 gates.
template<bool PAD, bool SEQOUT, bool INIT, bool WROUT>
__global__ __launch_bounds__(512)
__attribute__((amdgpu_waves_per_eu(2, 2)))
void recg_kernel(const float* __restrict__ zx,    // [tlen][B][512] (bias incl)
                 const float* __restrict__ U,     // PAD ? [100][400] : [128][512]
                 float* __restrict__ outp,        // SEQOUT: h1seq chunk [t][B][100]; WROUT: h2 [B][128]
                 float* __restrict__ cbuf,        // [B][128] c carry
                 float* __restrict__ hbuf,        // [B][128] h carry
                 int tlen)
{
    constexpr int HLD = 136;             // shorts per row (272 B = 17*16, b128-aligned)
    constexpr int HSZ = 16 * HLD;
    __shared__ __align__(16) short hsH[2][HSZ];  // h hi-bf16, double-buffered
    __shared__ __align__(16) short hsL[2][HSZ];  // h lo-bf16

    const int tid = threadIdx.x;
    const int wv = tid >> 6;             // 0..7: unit group
    const int lane = tid & 63;
    const int lm = lane & 15;
    const int lq = lane >> 4;
    const int u = 16 * wv + lm;          // unit owned by this lane
    const int blk16 = blockIdx.x * 16;

    // ---- one-time B-frag load: 4 gates x 4 ktiles x (hi,lo) = 128 VGPRs ----
#define BDECL(ga) \
    s8v bh##ga##_0, bl##ga##_0, bh##ga##_1, bl##ga##_1, \
        bh##ga##_2, bl##ga##_2, bh##ga##_3, bl##ga##_3; \
    load_bf_<PAD>(U, u, ga, 0, lq, bh##ga##_0, bl##ga##_0); \
    load_bf_<PAD>(U, u, ga, 1, lq, bh##ga##_1, bl##ga##_1); \
    load_bf_<PAD>(U, u, ga, 2, lq, bh##ga##_2, bl##ga##_2); \
    load_bf_<PAD>(U, u, ga, 3, lq, bh##ga##_3, bl##ga##_3);
    FOR_GA(BDECL)
#undef BDECL

    // ---- init h(0) into buffer 0 (pre-split) ----
    if (INIT) {
        for (int i = tid; i < HSZ; i += 512) { hsH[0][i] = 0; hsL[0][i] = 0; }
    } else {
        int row = tid >> 5, c4 = (tid & 31) * 4;   // 512 thr cover 16x128 f4-wise
        f4v hvv = *(const f4v*)&hbuf[(size_t)(blk16 + row) * 128 + c4];
        short hb, lb;
        bsplit_(hvv.x, hb, lb); hsH[0][row * HLD + c4 + 0] = hb; hsL[0][row * HLD + c4 + 0] = lb;
        bsplit_(hvv.y, hb, lb); hsH[0][row * HLD + c4 + 1] = hb; hsL[0][row * HLD + c4 + 1] = lb;
        bsplit_(hvv.z, hb, lb); hsH[0][row * HLD + c4 + 2] = hb; hsL[0][row * HLD + c4 + 2] = lb;
        bsplit_(hvv.w, hb, lb); hsH[0][row * HLD + c4 + 3] = hb; hsL[0][row * HLD + c4 + 3] = lb;
    }
    // ---- c state: rows lq*4+r, unit u ----
    f4v cst = {0.f, 0.f, 0.f, 0.f};
    if (!INIT) {
        const float* pc = cbuf + (size_t)(blk16 + lq * 4) * 128 + u;
        cst = (f4v){pc[0], pc[128], pc[256], pc[384]};
    }
    // ---- zc = zx(t=0) ----
    f4v zc0, zc1, zc2, zc3, zn0, zn1, zn2, zn3;
#define ZLD(ga, tt, dst) { \
    const float* p = zx + ((size_t)(tt) * BATCH + blk16 + lq * 4) * 512 + (ga) * 128 + u; \
    dst##ga = (f4v){p[0], p[512], p[1024], p[1536]}; }
    ZLD(0, 0, zc) ZLD(1, 0, zc) ZLD(2, 0, zc) ZLD(3, 0, zc)
    __syncthreads();

#define MKT(kt) { \
    const s8v ah = *(const s8v*)&hsH[cur][lm * HLD + (kt) * 32 + lq * 8]; \
    const s8v al = *(const s8v*)&hsL[cur][lm * HLD + (kt) * 32 + lq * 8]; \
    ac0 = __builtin_amdgcn_mfma_f32_16x16x32_bf16(ah, bh0_##kt, ac0, 0, 0, 0); \
    ac0 = __builtin_amdgcn_mfma_f32_16x16x32_bf16(al, bh0_##kt, ac0, 0, 0, 0); \
    ac0 = __builtin_amdgcn_mfma_f32_16x16x32_bf16(ah, bl0_##kt, ac0, 0, 0, 0); \
    ac1 = __builtin_amdgcn_mfma_f32_16x16x32_bf16(ah, bh1_##kt, ac1, 0, 0, 0); \
    ac1 = __builtin_amdgcn_mfma_f32_16x16x32_bf16(al, bh1_##kt, ac1, 0, 0, 0); \
    ac1 = __builtin_amdgcn_mfma_f32_16x16x32_bf16(ah, bl1_##kt, ac1, 0, 0, 0); \
    ac2 = __builtin_amdgcn_mfma_f32_16x16x32_bf16(ah, bh2_##kt, ac2, 0, 0, 0); \
    ac2 = __builtin_amdgcn_mfma_f32_16x16x32_bf16(al, bh2_##kt, ac2, 0, 0, 0); \
    ac2 = __builtin_amdgcn_mfma_f32_16x16x32_bf16(ah, bl2_##kt, ac2, 0, 0, 0); \
    ac3 = __builtin_amdgcn_mfma_f32_16x16x32_bf16(ah, bh3_##kt, ac3, 0, 0, 0); \
    ac3 = __builtin_amdgcn_mfma_f32_16x16x32_bf16(al, bh3_##kt, ac3, 0, 0, 0); \
    ac3 = __builtin_amdgcn_mfma_f32_16x16x32_bf16(ah, bl3_##kt, ac3, 0, 0, 0); }

#pragma unroll 1
    for (int t = 0; t < tlen; ++t) {
        const int cur = t & 1, nxt = cur ^ 1;
        // zn prefetch (issued first; covered by MFMA+gate work)
        int tn = (t + 1 < tlen) ? t + 1 : t;
        ZLD(0, tn, zn) ZLD(1, tn, zn) ZLD(2, tn, zn) ZLD(3, tn, zn)
        // MFMA: 4 gate slots, acc init = zc
        f4v ac0 = zc0, ac1 = zc1, ac2 = zc2, ac3 = zc3;
        MKT(0) MKT(1) MKT(2) MKT(3)
        // gates fully in registers
        f4v iv = sig4_(ac0), fv = sig4_(ac1), gv = relu4_(ac2), ov = sig4_(ac3);
        cst = fv * cst + iv * gv;
        f4v hv = ov * relu4_(cst);
        // split + store h (pre-split) to next buffer
        short hb, lb;
        bsplit_(hv.x, hb, lb); hsH[nxt][(lq * 4 + 0) * HLD + u] = hb; hsL[nxt][(lq * 4 + 0) * HLD + u] = lb;
        bsplit_(hv.y, hb, lb); hsH[nxt][(lq * 4 + 1) * HLD + u] = hb; hsL[nxt][(lq * 4 + 1) * HLD + u] = lb;
        bsplit_(hv.z, hb, lb); hsH[nxt][(lq * 4 + 2) * HLD + u] = hb; hsL[nxt][(lq * 4 + 2) * HLD + u] = lb;
        bsplit_(hv.w, hb, lb); hsH[nxt][(lq * 4 + 3) * HLD + u] = hb; hsL[nxt][(lq * 4 + 3) * HLD + u] = lb;
        if (SEQOUT) {
            if (!PAD || u < 100) {
                float* po = outp + ((size_t)t * BATCH + blk16 + lq * 4) * 100 + u;
                po[0] = hv.x; po[100] = hv.y; po[200] = hv.z; po[300] = hv.w;
            }
        }
        __syncthreads();
        zc0 = zn0; zc1 = zn1; zc2 = zn2; zc3 = zn3;
    }
#undef MKT
#undef ZLD

    // ---- chunk carry + outputs (h reconstructed hi+lo) ----
    const int fin = tlen & 1;
    {
        int row = tid >> 5, c4 = (tid & 31) * 4;
        f4v hvv;
        hvv.x = bf2f_(hsH[fin][row * HLD + c4 + 0]) + bf2f_(hsL[fin][row * HLD + c4 + 0]);
        hvv.y = bf2f_(hsH[fin][row * HLD + c4 + 1]) + bf2f_(hsL[fin][row * HLD + c4 + 1]);
        hvv.z = bf2f_(hsH[fin][row * HLD + c4 + 2]) + bf2f_(hsL[fin][row * HLD + c4 + 2]);
        hvv.w = bf2f_(hsH[fin][row * HLD + c4 + 3]) + bf2f_(hsL[fin][row * HLD + c4 + 3]);
        *(f4v*)&hbuf[(size_t)(blk16 + row) * 128 + c4] = hvv;
        if (WROUT) *(f4v*)&outp[(size_t)(blk16 + row) * 128 + c4] = hvv;
    }
    {
        float* pc = cbuf + (size_t)(blk16 + lq * 4) * 128 + u;
        pc[0] = cst.x; pc[128] = cst.y; pc[256] = cst.z; pc[384] = cst.w;
    }
}

// =================== layer-1 projection, gate-padded output ===================
__global__ __launch_bounds__(256, 2)
void proj1p_kernel(const float* __restrict__ x, const float* __restrict__ W1,
                   const float* __restrict__ b1, float* __restrict__ out, int t0)
{
    constexpr int LD = 132;
    __shared__ __align__(16) float As[32 * LD];
    __shared__ __align__(16) float Ws[32 * LD];
    const int tid = threadIdx.x;
    const int b = blockIdx.x;
    const int c0 = blockIdx.y * 128;
    const int ty = tid >> 4, tx = tid & 15;
    const float* A = x + ((size_t)b * T_SEQ + t0) * IN_DIM;

#define PACC(i) f4v accL##i = {0.f,0.f,0.f,0.f}; f4v accR##i = {0.f,0.f,0.f,0.f};
    PACC(0) PACC(1) PACC(2) PACC(3) PACC(4) PACC(5) PACC(6) PACC(7)
#undef PACC

    for (int kk = 0; kk < IN_DIM; kk += 32) {
        __syncthreads();
#pragma unroll
        for (int i = 0; i < 4; ++i) {
            int idx = tid + i * 256;
            int row = idx >> 3, kg = idx & 7;
            int k = kk + kg * 4;
            f4v v = *(const f4v*)&A[(size_t)row * IN_DIM + k];
            As[(kg * 4 + 0) * LD + row] = v.x;
            As[(kg * 4 + 1) * LD + row] = v.y;
            As[(kg * 4 + 2) * LD + row] = v.z;
            As[(kg * 4 + 3) * LD + row] = v.w;
        }
#pragma unroll
        for (int i = 0; i < 4; ++i) {
            int idx = tid + i * 256;
            int k = idx >> 5, cg = idx & 31;
            int gk = kk + k;
            int gcp = c0 + cg * 4;
            int gate = gcp >> 7, ub = gcp & 127;
            f4v v;
            v.x = (ub + 0 < 100) ? W1[(size_t)gk * 400 + gate * 100 + ub + 0] : 0.f;
            v.y = (ub + 1 < 100) ? W1[(size_t)gk * 400 + gate * 100 + ub + 1] : 0.f;
            v.z = (ub + 2 < 100) ? W1[(size_t)gk * 400 + gate * 100 + ub + 2] : 0.f;
            v.w = (ub + 3 < 100) ? W1[(size_t)gk * 400 + gate * 100 + ub + 3] : 0.f;
            *(f4v*)&Ws[k * LD + cg * 4] = v;
        }
        __syncthreads();
#pragma unroll
        for (int k = 0; k < 32; ++k) {
            f4v av0 = *(const f4v*)&As[k * LD + ty * 8];
            f4v av1 = *(const f4v*)&As[k * LD + ty * 8 + 4];
            f4v b0v = *(const f4v*)&Ws[k * LD + tx * 8];
            f4v b1v = *(const f4v*)&Ws[k * LD + tx * 8 + 4];
#define PFMA(i, s) accL##i += (s) * b0v; accR##i += (s) * b1v;
            PFMA(0, av0.x) PFMA(1, av0.y) PFMA(2, av0.z) PFMA(3, av0.w)
            PFMA(4, av1.x) PFMA(5, av1.y) PFMA(6, av1.z) PFMA(7, av1.w)
#undef PFMA
        }
    }

    const int cb = c0 + tx * 8;
    f4v bL, bR;
#pragma unroll
    for (int j = 0; j < 4; ++j) {
        int gate = (cb + j) >> 7, uu = (cb + j) & 127;
        bL[j] = (uu < 100) ? b1[gate * 100 + uu] : 0.f;
    }
#pragma unroll
    for (int j = 0; j < 4; ++j) {
        int gate = (cb + 4 + j) >> 7, uu = (cb + 4 + j) & 127;
        bR[j] = (uu < 100) ? b1[gate * 100 + uu] : 0.f;
    }
#define PST(i) { \
        int tl = ty * 8 + i; \
        size_t orow = (size_t)tl * BATCH + b; \
        f4v vL = accL##i + bL; *(f4v*)&out[orow * 512 + cb] = vL; \
        f4v vR = accR##i + bR; *(f4v*)&out[orow * 512 + cb + 4] = vR; }
    PST(0) PST(1) PST(2) PST(3) PST(4) PST(5) PST(6) PST(7)
#undef PST
}

// =================== generic projection GEMM (layer 2) ===================
#define PREP8(M)  M(0) M(1) M(2) M(3) M(4) M(5) M(6) M(7)
template<int K, int N, bool SWAP>
__global__ __launch_bounds__(256, 2)
void proj_kernel(const float* __restrict__ A, const float* __restrict__ W,
                 const float* __restrict__ bias, float* __restrict__ out)
{
    constexpr int LD = 132;
    __shared__ __align__(16) float As[32 * LD];
    __shared__ __align__(16) float Ws[32 * LD];
    const int tid = threadIdx.x;
    const int r0 = blockIdx.x * 128;
    const int c0 = blockIdx.y * 128;
    const int ty = tid >> 4, tx = tid & 15;

#define PACC(i) f4v accL##i = {0.f,0.f,0.f,0.f}; f4v accR##i = {0.f,0.f,0.f,0.f};
    PREP8(PACC)
#undef PACC

    for (int kk = 0; kk < K; kk += 32) {
        __syncthreads();
#pragma unroll
        for (int i = 0; i < 4; ++i) {
            int idx = tid + i * 256;
            int row = idx >> 3, kg = idx & 7;
            int k = kk + kg * 4;
            f4v v = {0.f, 0.f, 0.f, 0.f};
            if (k < K) v = *(const f4v*)&A[(size_t)(r0 + row) * K + k];
            As[(kg * 4 + 0) * LD + row] = v.x;
            As[(kg * 4 + 1) * LD + row] = v.y;
            As[(kg * 4 + 2) * LD + row] = v.z;
            As[(kg * 4 + 3) * LD + row] = v.w;
        }
#pragma unroll
        for (int i = 0; i < 4; ++i) {
            int idx = tid + i * 256;
            int k = idx >> 5, cg = idx & 31;
            int gk = kk + k, gc = c0 + cg * 4;
            f4v v = {0.f, 0.f, 0.f, 0.f};
            if (gk < K && gc < N) v = *(const f4v*)&W[(size_t)gk * N + gc];
            *(f4v*)&Ws[k * LD + cg * 4] = v;
        }
        __syncthreads();
#pragma unroll
        for (int k = 0; k < 32; ++k) {
            f4v av0 = *(const f4v*)&As[k * LD + ty * 8];
            f4v av1 = *(const f4v*)&As[k * LD + ty * 8 + 4];
            f4v b0v = *(const f4v*)&Ws[k * LD + tx * 8];
            f4v b1v = *(const f4v*)&Ws[k * LD + tx * 8 + 4];
#define PFMA(i, s) accL##i += (s) * b0v; accR##i += (s) * b1v;
            PFMA(0, av0.x) PFMA(1, av0.y) PFMA(2, av0.z) PFMA(3, av0.w)
            PFMA(4, av1.x) PFMA(5, av1.y) PFMA(6, av1.z) PFMA(7, av1.w)
#undef PFMA
        }
    }

    const int cb = c0 + tx * 8;
    f4v bL, bR;
#pragma unroll
    for (int j = 0; j < 4; ++j) bL[j] = (cb + j < N) ? bias[cb + j] : 0.f;
#pragma unroll
    for (int j = 0; j < 4; ++j) bR[j] = (cb + 4 + j < N) ? bias[cb + 4 + j] : 0.f;
#define PST(i) { \
        int r = r0 + ty * 8 + i; \
        size_t orow = SWAP ? ((size_t)(r & 255) * BATCH + (r >> 8)) : (size_t)r; \
        if (cb < N)     { f4v v = accL##i + bL; *(f4v*)&out[orow * N + cb] = v; } \
        if (cb + 4 < N) { f4v v = accR##i + bR; *(f4v*)&out[orow * N + cb + 4] = v; } }
    PREP8(PST)
#undef PST
}

// =================== dense + softmax ===================
__global__ __launch_bounds__(64, 1)
void dense_softmax_kernel(const float* __restrict__ h2, const float* __restrict__ Wd,
                          const float* __restrict__ bd, float* __restrict__ out)
{
    const int b = blockIdx.x;
    const int k = threadIdx.x;
    __shared__ __align__(16) float hsm[H2];
    if (k < H2 / 4) ((f4v*)hsm)[k] = ((const f4v*)(h2 + (size_t)b * H2))[k];
    __syncthreads();

    float logit = -1e30f;
    if (k < NCLS) {
        float acc = bd[k];
#pragma unroll
        for (int d = 0; d < H2; ++d) acc += hsm[d] * Wd[d * NCLS + k];
        logit = acc;
    }
    float m = logit;
#pragma unroll
    for (int off = 32; off >= 1; off >>= 1) m = fmaxf(m, __shfl_xor(m, off, 64));
    float e = (k < NCLS) ? __expf(logit - m) : 0.0f;
    float s = e;
#pragma unroll
    for (int off = 32; off >= 1; off >>= 1) s += __shfl_xor(s, off, 64);
    if (k < NCLS) out[(size_t)b * NCLS + k] = e / s;
}

// =================== fallback (round-1) kernels ===================
__global__ __launch_bounds__(448, 1)
void lstm1_fb(const float* __restrict__ x, const float* __restrict__ W1,
              const float* __restrict__ U1, const float* __restrict__ b1,
              float* __restrict__ h1out)
{
    const int b = blockIdx.x;
    const int k = threadIdx.x;
    __shared__ __align__(16) float xs[IN_DIM];
    __shared__ __align__(16) float hs[H1];
    __shared__ __align__(16) float zs[4 * H1];
    float w1r[IN_DIM];
    float u1r[H1];
    float bias = 0.0f;
    if (k < 4 * H1) {
        bias = b1[k];
#pragma unroll
        for (int d = 0; d < IN_DIM; ++d) w1r[d] = W1[d * (4 * H1) + k];
#pragma unroll
        for (int j = 0; j < H1; ++j) u1r[j] = U1[j * (4 * H1) + k];
    }
    if (k < H1) hs[k] = 0.0f;
    if (k < IN_DIM / 4)
        ((float4*)xs)[k] = ((const float4*)(x + ((size_t)b * T_SEQ) * IN_DIM))[k];
    float c = 0.0f;
    __syncthreads();
    for (int t = 0; t < T_SEQ; ++t) {
        if (k < 4 * H1) {
            float acc0 = bias, acc1 = 0.f, acc2 = 0.f, acc3 = 0.f;
#pragma unroll
            for (int q = 0; q < IN_DIM / 4; ++q) {
                float4 xv = ((const float4*)xs)[q];
                acc0 += xv.x * w1r[4 * q]; acc1 += xv.y * w1r[4 * q + 1];
                acc2 += xv.z * w1r[4 * q + 2]; acc3 += xv.w * w1r[4 * q + 3];
            }
#pragma unroll
            for (int q = 0; q < H1 / 4; ++q) {
                float4 hv = ((const float4*)hs)[q];
                acc0 += hv.x * u1r[4 * q]; acc1 += hv.y * u1r[4 * q + 1];
                acc2 += hv.z * u1r[4 * q + 2]; acc3 += hv.w * u1r[4 * q + 3];
            }
            float zv = (acc0 + acc1) + (acc2 + acc3);
            zs[k] = (k >= 2 * H1 && k < 3 * H1) ? fmaxf(zv, 0.0f) : sigmoidf_(zv);
        }
        __syncthreads();
        if (k < H1) {
            float i = zs[k], f = zs[k + H1], g = zs[k + 2 * H1], o = zs[k + 3 * H1];
            c = f * c + i * g;
            float h = o * fmaxf(c, 0.0f);
            hs[k] = h;
            h1out[((size_t)t * BATCH + b) * H1 + k] = h;
        }
        int tn = t + 1;
        if (tn < T_SEQ && k < IN_DIM / 4)
            ((float4*)xs)[k] = ((const float4*)(x + ((size_t)b * T_SEQ + tn) * IN_DIM))[k];
        __syncthreads();
    }
}

__global__ __launch_bounds__(512, 1)
void lstm2_fb(const float* __restrict__ h1in, const float* __restrict__ W2,
              const float* __restrict__ U2, const float* __restrict__ b2,
              float* __restrict__ h2out)
{
    const int b = blockIdx.x;
    const int k = threadIdx.x;
    __shared__ __align__(16) float ps[H1];
    __shared__ __align__(16) float hs[H2];
    __shared__ __align__(16) float zs[4 * H2];
    float w2r[H1];
    float u2r[H2];
    float bias = b2[k];
#pragma unroll
    for (int j = 0; j < H1; ++j) w2r[j] = W2[j * (4 * H2) + k];
#pragma unroll
    for (int j = 0; j < H2; ++j) u2r[j] = U2[j * (4 * H2) + k];
    if (k < H2) hs[k] = 0.0f;
    if (k < H1 / 4)
        ((float4*)ps)[k] = ((const float4*)(h1in + (size_t)b * H1))[k];
    float c = 0.0f;
    float hlast = 0.0f;
    __syncthreads();
    for (int t = 0; t < T_SEQ; ++t) {
        float acc0 = bias, acc1 = 0.f, acc2 = 0.f, acc3 = 0.f;
#pragma unroll
        for (int q = 0; q < H1 / 4; ++q) {
            float4 pv = ((const float4*)ps)[q];
            acc0 += pv.x * w2r[4 * q]; acc1 += pv.y * w2r[4 * q + 1];
            acc2 += pv.z * w2r[4 * q + 2]; acc3 += pv.w * w2r[4 * q + 3];
        }
#pragma unroll
        for (int q = 0; q < H2 / 4; ++q) {
            float4 hv = ((const float4*)hs)[q];
            acc0 += hv.x * u2r[4 * q]; acc1 += hv.y * u2r[4 * q + 1];
            acc2 += hv.z * u2r[4 * q + 2]; acc3 += hv.w * u2r[4 * q + 3];
        }
        float zv = (acc0 + acc1) + (acc2 + acc3);
        zs[k] = (k >= 2 * H2 && k < 3 * H2) ? fmaxf(zv, 0.0f) : sigmoidf_(zv);
        __syncthreads();
        if (k < H2) {
            float i = zs[k], f = zs[k + H2], g = zs[k + 2 * H2], o = zs[k + 3 * H2];
            c = f * c + i * g;
            hlast = o * fmaxf(c, 0.0f);
            hs[k] = hlast;
        }
        int tn = t + 1;
        if (tn < T_SEQ && k < H1 / 4)
            ((float4*)ps)[k] = ((const float4*)(h1in + ((size_t)tn * BATCH + b) * H1))[k];
        __syncthreads();
    }
    if (k < H2) h2out[(size_t)b * H2 + k] = hlast;
}

extern "C" void kernel_launch(void* const* d_in, const int* in_sizes, int n_in,
                              void* d_out, int out_size, void* d_ws, size_t ws_size,
                              hipStream_t stream) {
    const float* x  = (const float*)d_in[0];
    const float* W1 = (const float*)d_in[1];
    const float* U1 = (const float*)d_in[2];
    const float* b1 = (const float*)d_in[3];
    const float* W2 = (const float*)d_in[4];
    const float* U2 = (const float*)d_in[5];
    const float* b2 = (const float*)d_in[6];
    const float* Wd = (const float*)d_in[7];
    const float* bd = (const float*)d_in[8];
    float* out = (float*)d_out;

    const int TC = T_SEQ / 2;                                   // 128-step chunks
    const size_t zx_elems = (size_t)TC * BATCH * 512;           // 134.2 MB
    const size_t h1_elems = (size_t)T_SEQ * BATCH * H1;         // 52.4 MB
    const size_t st_elems = (size_t)BATCH * H2;
    const size_t need = (zx_elems + h1_elems + 5 * st_elems) * sizeof(float);  // ~188 MB

    if (ws_size >= need) {
        float* zxbuf = (float*)d_ws;
        float* h1buf = zxbuf + zx_elems;
        float* c1buf = h1buf + h1_elems;
        float* hc1buf = c1buf + st_elems;
        float* c2buf = hc1buf + st_elems;
        float* hc2buf = c2buf + st_elems;
        float* h2buf = hc2buf + st_elems;

        // ---- layer 1, chunk A (t 0..127) ----
        hipLaunchKernelGGL(proj1p_kernel, dim3(BATCH, 4), dim3(256), 0, stream,
                           x, W1, b1, zxbuf, 0);
        hipLaunchKernelGGL((recg_kernel<true, true, true, false>), dim3(32), dim3(512), 0, stream,
                           zxbuf, U1, h1buf, c1buf, hc1buf, TC);
        // ---- layer 1, chunk B (t 128..255) ----
        hipLaunchKernelGGL(proj1p_kernel, dim3(BATCH, 4), dim3(256), 0, stream,
                           x, W1, b1, zxbuf, TC);
        hipLaunchKernelGGL((recg_kernel<true, true, false, false>), dim3(32), dim3(512), 0, stream,
                           zxbuf, U1, h1buf + (size_t)TC * BATCH * H1, c1buf, hc1buf, TC);
        // ---- layer 2, chunk A ----
        hipLaunchKernelGGL((proj_kernel<H1, 4 * H2, false>), dim3(512, 4), dim3(256), 0, stream,
                           h1buf, W2, b2, zxbuf);
        hipLaunchKernelGGL((recg_kernel<false, false, true, false>), dim3(32), dim3(512), 0, stream,
                           zxbuf, U2, (float*)nullptr, c2buf, hc2buf, TC);
        // ---- layer 2, chunk B ----
        hipLaunchKernelGGL((proj_kernel<H1, 4 * H2, false>), dim3(512, 4), dim3(256), 0, stream,
                           h1buf + (size_t)TC * BATCH * H1, W2, b2, zxbuf);
        hipLaunchKernelGGL((recg_kernel<false, false, false, true>), dim3(32), dim3(512), 0, stream,
                           zxbuf, U2, h2buf, c2buf, hc2buf, TC);

        hipLaunchKernelGGL(dense_softmax_kernel, dim3(BATCH), dim3(64), 0, stream,
                           h2buf, Wd, bd, out);
    } else {
        // fallback: round-1 fused kernels (needs ~52.7 MB)
        float* h1buf = (float*)d_ws;
        float* h2buf = h1buf + h1_elems;
        hipLaunchKernelGGL(lstm1_fb, dim3(BATCH), dim3(448), 0, stream, x, W1, U1, b1, h1buf);
        hipLaunchKernelGGL(lstm2_fb, dim3(BATCH), dim3(512), 0, stream, h1buf, W2, U2, b2, h2buf);
        hipLaunchKernelGGL(dense_softmax_kernel, dim3(BATCH), dim3(64), 0, stream, h2buf, Wd, bd, out);
    }
}